// Round 10
// baseline (448.720 us; speedup 1.0000x reference)
//
#include <hip/hip_runtime.h>
#include <math.h>

// GATv2, 3 layers. N=50000, E=500000, F_IN=128, H=4, D=32 (layers 0/1), HO=6, C=40 (layer 2).
// CSR-by-dst -> per-node fused softmax aggregation (no float atomics, no max tracking:
// logits are O(1) for this model), fp32 GEMMs, residual head-mean folded into small GEMM.
// Round 10: 8 edges in flight per wave in both agg kernels (latency residue per round-9
// counters: VALU 52% / mem 51% / occ 57%); GEMM gains register prefetch of next chunk
// issued before the FMA block (BK=32 single buffer, 2 barriers, dynamic loop).

#define LRELU(x) ((x) >= 0.f ? (x) : 0.2f * (x))

// ---------------- CSR build ----------------
__global__ void k_zero(int* __restrict__ cnt, int* __restrict__ fill, int N) {
  int i = blockIdx.x * blockDim.x + threadIdx.x;
  if (i < N) { cnt[i] = 0; fill[i] = 0; }
}

__global__ void k_count(const int* __restrict__ dst, int* __restrict__ cnt, int E) {
  int e = blockIdx.x * blockDim.x + threadIdx.x;
  if (e < E) atomicAdd(&cnt[dst[e]], 1);
}

__global__ void k_scan1(const int* __restrict__ cnt, int* __restrict__ row_ptr,
                        int* __restrict__ bsum, int N) {
  __shared__ int s[256];
  int tid = threadIdx.x;
  int i = blockIdx.x * 256 + tid;
  int v = (i < N) ? cnt[i] : 0;
  s[tid] = v;
  __syncthreads();
  for (int off = 1; off < 256; off <<= 1) {
    int t = (tid >= off) ? s[tid - off] : 0;
    __syncthreads();
    s[tid] += t;
    __syncthreads();
  }
  if (i < N) row_ptr[i] = s[tid] - v;
  if (tid == 255) bsum[blockIdx.x] = s[255];
}

__global__ void k_scan2(int* __restrict__ bsum, int nb) {
  __shared__ int s[256];
  int t = threadIdx.x;
  int v = (t < nb) ? bsum[t] : 0;
  s[t] = v;
  __syncthreads();
  for (int off = 1; off < 256; off <<= 1) {
    int tt = (t >= off) ? s[t - off] : 0;
    __syncthreads();
    s[t] += tt;
    __syncthreads();
  }
  if (t < nb) bsum[t] = s[t] - v;
}

__global__ void k_scan3(int* __restrict__ row_ptr, const int* __restrict__ bsum, int N, int E) {
  int i = blockIdx.x * blockDim.x + threadIdx.x;
  if (i < N) row_ptr[i] += bsum[i >> 8];
  else if (i == N) row_ptr[N] = E;
}

__global__ void k_scatter(const int* __restrict__ src, const int* __restrict__ dst,
                          const int* __restrict__ row_ptr, int* __restrict__ fill,
                          int* __restrict__ csr_src, int E) {
  int e = blockIdx.x * blockDim.x + threadIdx.x;
  if (e >= E) return;
  int d = dst[e];
  int pos = row_ptr[d] + atomicAdd(&fill[d], 1);
  csr_src[pos] = src[e];
}

// ---------------- Wres2 head-mean fold ----------------
__global__ void k_wmean(const float* __restrict__ wres2, float* __restrict__ wm) {
  int i = blockIdx.x * blockDim.x + threadIdx.x;
  if (i >= 128 * 40) return;
  int k = i / 40, c = i % 40;
  float s = 0.f;
#pragma unroll
  for (int ho = 0; ho < 6; ++ho) s += wres2[k * 240 + ho * 40 + c];
  wm[i] = s * (1.0f / 6.0f);
}

// ---------------- GEMM: C[N][LDC] = A[N][128] @ B[128][LDC], LDC in {128,240} ----------------
// 64x128 tile, 256 threads, 4x8/thread. Single LDS buffer BK=32, 2 barriers per chunk.
// Register prefetch: loads for chunk i+1 are issued BEFORE compute(i), drain during FMAs.
template <int LDC>
__global__ __launch_bounds__(256) void k_gemm(const float* __restrict__ A,
                                              const float* __restrict__ B,
                                              float* __restrict__ C, int N) {
  __shared__ __align__(16) float As[32][64];    // [k][row], 8KB
  __shared__ __align__(16) float Bs[32][128];   // [k][col], 16KB
  const int tid = threadIdx.x;
  const int row0 = blockIdx.x * 64;
  const int col_base = (blockIdx.y == 0) ? 0 : (LDC - 128);
  const int ty = tid >> 4, tx = tid & 15;
  const int r0 = ty * 4;
  const int arow = tid & 63;
  const int akc = (tid >> 6) * 8;   // 0,8,16,24 (wave-uniform)
  int gra = row0 + arow;
  if (gra >= N) gra = N - 1;
  const float* Ap = A + (size_t)gra * 128 + akc;
  const int f0 = tid * 4;
  const int br0 = f0 >> 7, bc0 = f0 & 127;

  float acc[4][8] = {};

  // prologue: chunk 0 into staging regs
  float4 a0 = *(const float4*)(Ap + 0);
  float4 a1 = *(const float4*)(Ap + 4);
  float4 bv0 = *(const float4*)&B[(size_t)(br0 + 0) * LDC + col_base + bc0];
  float4 bv1 = *(const float4*)&B[(size_t)(br0 + 8) * LDC + col_base + bc0];
  float4 bv2 = *(const float4*)&B[(size_t)(br0 + 16) * LDC + col_base + bc0];
  float4 bv3 = *(const float4*)&B[(size_t)(br0 + 24) * LDC + col_base + bc0];

#pragma unroll 1
  for (int i = 0; i < 4; ++i) {
    __syncthreads();   // previous chunk's LDS reads done
    As[akc + 0][arow] = a0.x;
    As[akc + 1][arow] = a0.y;
    As[akc + 2][arow] = a0.z;
    As[akc + 3][arow] = a0.w;
    As[akc + 4][arow] = a1.x;
    As[akc + 5][arow] = a1.y;
    As[akc + 6][arow] = a1.z;
    As[akc + 7][arow] = a1.w;
    *(float4*)&Bs[br0 + 0][bc0] = bv0;
    *(float4*)&Bs[br0 + 8][bc0] = bv1;
    *(float4*)&Bs[br0 + 16][bc0] = bv2;
    *(float4*)&Bs[br0 + 24][bc0] = bv3;
    if (i < 3) {
      const int kk = (i + 1) * 32;   // issue next-chunk loads; drain during compute
      a0 = *(const float4*)(Ap + kk);
      a1 = *(const float4*)(Ap + kk + 4);
      bv0 = *(const float4*)&B[(size_t)(kk + br0 + 0) * LDC + col_base + bc0];
      bv1 = *(const float4*)&B[(size_t)(kk + br0 + 8) * LDC + col_base + bc0];
      bv2 = *(const float4*)&B[(size_t)(kk + br0 + 16) * LDC + col_base + bc0];
      bv3 = *(const float4*)&B[(size_t)(kk + br0 + 24) * LDC + col_base + bc0];
    }
    __syncthreads();   // LDS chunk i visible
#pragma unroll
    for (int k = 0; k < 32; ++k) {
      float a[4], b[8];
      *(float4*)&a[0] = *(const float4*)&As[k][r0];
      *(float4*)&b[0] = *(const float4*)&Bs[k][tx * 4];
      *(float4*)&b[4] = *(const float4*)&Bs[k][64 + tx * 4];
#pragma unroll
      for (int ii = 0; ii < 4; ++ii)
#pragma unroll
        for (int jj = 0; jj < 8; ++jj) acc[ii][jj] += a[ii] * b[jj];
    }
  }

  const int gc_lo = col_base + tx * 4;
  const int gc_hi = col_base + 64 + tx * 4;
  const bool lo_ok = (blockIdx.y == 0) || (gc_lo >= 128);
#pragma unroll
  for (int i = 0; i < 4; ++i) {
    int gr = row0 + r0 + i;
    if (gr < N) {
      if (lo_ok) *(float4*)&C[(size_t)gr * LDC + gc_lo] = *(float4*)&acc[i][0];
      *(float4*)&C[(size_t)gr * LDC + gc_hi] = *(float4*)&acc[i][4];
    }
  }
}

// ---------------- res_mean[N][40] = A[N][128] @ Wm[128][40] ----------------
__global__ __launch_bounds__(256) void k_resmean(const float* __restrict__ A,
                                                 const float* __restrict__ Wm,
                                                 float* __restrict__ out, int N) {
  __shared__ float w[128 * 40];
  for (int i = threadIdx.x; i < 128 * 40; i += 256) w[i] = Wm[i];
  __syncthreads();
  int r = blockIdx.x * 256 + threadIdx.x;
  if (r >= N) return;
  float acc[40] = {};
  for (int k = 0; k < 128; k += 4) {
    float4 hv = *(const float4*)&A[(size_t)r * 128 + k];
#pragma unroll
    for (int j = 0; j < 40; ++j)
      acc[j] += hv.x * w[(k + 0) * 40 + j] + hv.y * w[(k + 1) * 40 + j] +
                hv.z * w[(k + 2) * 40 + j] + hv.w * w[(k + 3) * 40 + j];
  }
#pragma unroll
  for (int j = 0; j < 40; j += 4)
    *(float4*)&out[(size_t)r * 40 + j] = make_float4(acc[j], acc[j + 1], acc[j + 2], acc[j + 3]);
}

// ---------------- Fused edge softmax + aggregate, layers 0/1 (H=4, D=32) ----------------
// One wave per node; 8 edges per iteration: each half-wave runs 4 load streams
// (edges p+half, p+2+half, p+4+half, p+6+half), 2 accumulator streams.
// 8-lane head groups; shuffle rounds interleaved across streams. No max tracking.
template <bool RES>
__global__ __launch_bounds__(256) void k_agg_fused(const float* __restrict__ feat,
                                                   const float* __restrict__ attn,
                                                   const int* __restrict__ row_ptr,
                                                   const int* __restrict__ csr_src,
                                                   const float* __restrict__ hres,
                                                   float* __restrict__ out, int N) {
  int wid = (blockIdx.x * 256 + threadIdx.x) >> 6;
  bool nok = wid < N;
  int n = nok ? wid : (N - 1);
  int lane = threadIdx.x & 63;
  int half = lane >> 5;
  int c = (lane & 31) * 4;
  float4 fd = *(const float4*)&feat[(size_t)n * 128 + c];
  float4 av = *(const float4*)&attn[c];
  int p0 = row_ptr[n], p1 = row_ptr[n + 1];
  float4 zero = {0.f, 0.f, 0.f, 0.f};
  float sA = 0.f, sB = 0.f;
  float4 aA = zero, aB = zero;
  for (int p = p0; p < p1; p += 8) {
    int pe_[4];
    bool v_[4];
    int i_[4];
#pragma unroll
    for (int j = 0; j < 4; ++j) {
      pe_[j] = p + 2 * j + half;
      v_[j] = pe_[j] < p1;
      i_[j] = csr_src[v_[j] ? pe_[j] : p0];
    }
    float4 f0v = *(const float4*)&feat[(size_t)i_[0] * 128 + c];
    float4 f1v = *(const float4*)&feat[(size_t)i_[1] * 128 + c];
    float4 f2v = *(const float4*)&feat[(size_t)i_[2] * 128 + c];
    float4 f3v = *(const float4*)&feat[(size_t)i_[3] * 128 + c];
    float x0 = av.x * LRELU(f0v.x + fd.x) + av.y * LRELU(f0v.y + fd.y) +
               av.z * LRELU(f0v.z + fd.z) + av.w * LRELU(f0v.w + fd.w);
    float x1 = av.x * LRELU(f1v.x + fd.x) + av.y * LRELU(f1v.y + fd.y) +
               av.z * LRELU(f1v.z + fd.z) + av.w * LRELU(f1v.w + fd.w);
    float x2 = av.x * LRELU(f2v.x + fd.x) + av.y * LRELU(f2v.y + fd.y) +
               av.z * LRELU(f2v.z + fd.z) + av.w * LRELU(f2v.w + fd.w);
    float x3 = av.x * LRELU(f3v.x + fd.x) + av.y * LRELU(f3v.y + fd.y) +
               av.z * LRELU(f3v.z + fd.z) + av.w * LRELU(f3v.w + fd.w);
    x0 += __shfl_xor(x0, 1);
    x1 += __shfl_xor(x1, 1);
    x2 += __shfl_xor(x2, 1);
    x3 += __shfl_xor(x3, 1);
    x0 += __shfl_xor(x0, 2);
    x1 += __shfl_xor(x1, 2);
    x2 += __shfl_xor(x2, 2);
    x3 += __shfl_xor(x3, 2);
    x0 += __shfl_xor(x0, 4);
    x1 += __shfl_xor(x1, 4);
    x2 += __shfl_xor(x2, 4);
    x3 += __shfl_xor(x3, 4);
    float e0 = v_[0] ? __expf(x0) : 0.f;
    float e1 = v_[1] ? __expf(x1) : 0.f;
    float e2 = v_[2] ? __expf(x2) : 0.f;
    float e3 = v_[3] ? __expf(x3) : 0.f;
    sA += e0 + e2;
    sB += e1 + e3;
    aA.x += e0 * f0v.x + e2 * f2v.x;
    aA.y += e0 * f0v.y + e2 * f2v.y;
    aA.z += e0 * f0v.z + e2 * f2v.z;
    aA.w += e0 * f0v.w + e2 * f2v.w;
    aB.x += e1 * f1v.x + e3 * f3v.x;
    aB.y += e1 * f1v.y + e3 * f3v.y;
    aB.z += e1 * f1v.z + e3 * f3v.z;
    aB.w += e1 * f1v.w + e3 * f3v.w;
  }
  // merge in-half streams (plain add), then cross-half via shfl
  sA += sB;
  aA.x += aB.x; aA.y += aB.y; aA.z += aB.z; aA.w += aB.w;
  float s2 = __shfl_xor(sA, 32);
  float4 a2;
  a2.x = __shfl_xor(aA.x, 32);
  a2.y = __shfl_xor(aA.y, 32);
  a2.z = __shfl_xor(aA.z, 32);
  a2.w = __shfl_xor(aA.w, 32);
  float ssum = sA + s2;
  float inv = (p1 > p0) ? 1.0f / ssum : 0.f;
  float4 r;
  r.x = (aA.x + a2.x) * inv;
  r.y = (aA.y + a2.y) * inv;
  r.z = (aA.z + a2.z) * inv;
  r.w = (aA.w + a2.w) * inv;
  if (RES) {
    float4 hv = *(const float4*)&hres[(size_t)n * 128 + c];
    r.x += hv.x; r.y += hv.y; r.z += hv.z; r.w += hv.w;
  }
  r.x = r.x > 0.f ? r.x : expm1f(r.x);
  r.y = r.y > 0.f ? r.y : expm1f(r.y);
  r.z = r.z > 0.f ? r.z : expm1f(r.z);
  r.w = r.w > 0.f ? r.w : expm1f(r.w);
  if (half == 0 && nok) *(float4*)&out[(size_t)n * 128 + c] = r;
}

// ---------------- Fused layer 2 (HO=6, C=40) + head-mean + residual -> d_out ----------------
// ONE wave per node; lane = ho*10 + t (60 active), float4 at ho*40+t*4.
// EIGHT edges in flight per iteration (8 gather streams, 4 accumulator streams).
__global__ __launch_bounds__(256) void k_agg2_fused(const float* __restrict__ feat2,
                                                    const float* __restrict__ attn2,
                                                    const int* __restrict__ row_ptr,
                                                    const int* __restrict__ csr_src,
                                                    const float* __restrict__ resm,
                                                    float* __restrict__ out, int N) {
  __shared__ float rs[4][240];
  int w = threadIdx.x >> 6;
  int wid = blockIdx.x * 4 + w;
  bool nok = wid < N;
  int n = nok ? wid : (N - 1);
  int lane = threadIdx.x & 63;
  bool act = lane < 60;
  int ho = lane / 10, t = lane % 10;
  int g0 = ho * 10;
  int fo = act ? (ho * 40 + t * 4) : 0;
  float4 zero = {0.f, 0.f, 0.f, 0.f};
  float4 fd = act ? *(const float4*)&feat2[(size_t)n * 240 + fo] : zero;
  float4 av = act ? *(const float4*)&attn2[fo] : zero;
  int p0 = row_ptr[n], p1 = row_ptr[n + 1];
  float s_[4];
  float4 a_[4];
#pragma unroll
  for (int j = 0; j < 4; ++j) { s_[j] = 0.f; a_[j] = zero; }
  for (int p = p0; p < p1; p += 8) {
    int idx[8];
    bool val[8];
#pragma unroll
    for (int j = 0; j < 8; ++j) {
      int pp = p + j;
      val[j] = pp < p1;
      idx[j] = csr_src[val[j] ? pp : p];
    }
    float4 f_[8];
#pragma unroll
    for (int j = 0; j < 8; ++j) f_[j] = *(const float4*)&feat2[(size_t)idx[j] * 240 + fo];
    float x_[8], aa_[8], S_[8];
#pragma unroll
    for (int j = 0; j < 8; ++j)
      x_[j] = av.x * LRELU(f_[j].x + fd.x) + av.y * LRELU(f_[j].y + fd.y) +
              av.z * LRELU(f_[j].z + fd.z) + av.w * LRELU(f_[j].w + fd.w);
    // 10-lane segmented reduce, 8 streams interleaved
#pragma unroll
    for (int j = 0; j < 8; ++j) aa_[j] = x_[j] + __shfl(x_[j], lane + 5);
#pragma unroll
    for (int j = 0; j < 8; ++j) S_[j] = aa_[j] + __shfl(aa_[j], lane + 1);
#pragma unroll
    for (int j = 0; j < 8; ++j) S_[j] = S_[j] + __shfl(S_[j], lane + 2);
#pragma unroll
    for (int j = 0; j < 8; ++j) S_[j] = S_[j] + __shfl(aa_[j], lane + 4);
#pragma unroll
    for (int j = 0; j < 8; ++j) {
      float l = __shfl(S_[j], g0);
      float pe = val[j] ? __expf(l) : 0.f;
      s_[j & 3] += pe;
      a_[j & 3].x += pe * f_[j].x;
      a_[j & 3].y += pe * f_[j].y;
      a_[j & 3].z += pe * f_[j].z;
      a_[j & 3].w += pe * f_[j].w;
    }
  }
  float ssum = (s_[0] + s_[1]) + (s_[2] + s_[3]);
  float4 at;
  at.x = (a_[0].x + a_[1].x) + (a_[2].x + a_[3].x);
  at.y = (a_[0].y + a_[1].y) + (a_[2].y + a_[3].y);
  at.z = (a_[0].z + a_[1].z) + (a_[2].z + a_[3].z);
  at.w = (a_[0].w + a_[1].w) + (a_[2].w + a_[3].w);
  float inv = (p1 > p0) ? 1.0f / ssum : 0.f;
  float4 r;
  r.x = at.x * inv;
  r.y = at.y * inv;
  r.z = at.z * inv;
  r.w = at.w * inv;
  if (act) *(float4*)&rs[w][fo] = r;
  __syncthreads();
  if (lane < 10 && nok) {
#pragma unroll
    for (int k = 0; k < 4; ++k) {
      int cc = t * 4 + k;
      float v = (rs[w][cc] + rs[w][40 + cc] + rs[w][80 + cc] + rs[w][120 + cc] +
                 rs[w][160 + cc] + rs[w][200 + cc]) * (1.0f / 6.0f) +
                resm[(size_t)n * 40 + cc];
      out[(size_t)n * 40 + cc] = v;
    }
  }
}

// ---------------- host ----------------
extern "C" void kernel_launch(void* const* d_in, const int* in_sizes, int n_in,
                              void* d_out, int out_size, void* d_ws, size_t ws_size,
                              hipStream_t stream) {
  const float* inputs = (const float*)d_in[0];
  const int* src = (const int*)d_in[1];
  const int* dst = (const int*)d_in[2];
  const float* W0 = (const float*)d_in[3];
  const float* attn0 = (const float*)d_in[4];
  const float* W1 = (const float*)d_in[5];
  const float* attn1 = (const float*)d_in[6];
  const float* W2 = (const float*)d_in[7];
  const float* attn2 = (const float*)d_in[8];
  const float* Wres2 = (const float*)d_in[9];
  const int N = in_sizes[0] / 128;
  const int E = in_sizes[1];

  char* base = (char*)d_ws;
  size_t off = 0;
  auto alloc = [&](size_t bytes) -> void* {
    void* q = base + off;
    off += (bytes + 255) & ~(size_t)255;
    return q;
  };
  int* cnt = (int*)alloc((size_t)N * 4);
  int* fill = (int*)alloc((size_t)N * 4);
  int* row_ptr = (int*)alloc((size_t)(N + 1) * 4);
  int* bsum = (int*)alloc(1024 * 4);
  int* csr_src = (int*)alloc((size_t)E * 4);
  float* F = (float*)alloc((size_t)N * 240 * 4);
  float* h1 = (float*)alloc((size_t)N * 128 * 4);
  float* h2 = (float*)alloc((size_t)N * 128 * 4);
  float* resm = (float*)alloc((size_t)N * 40 * 4);
  float* wm = (float*)alloc(128 * 40 * 4);
  (void)ws_size;

  const int nb1 = (N + 255) / 256;
  const int nrb = (N + 63) / 64;

  hipLaunchKernelGGL(k_zero, dim3((N + 255) / 256), dim3(256), 0, stream, cnt, fill, N);
  hipLaunchKernelGGL(k_count, dim3((E + 255) / 256), dim3(256), 0, stream, dst, cnt, E);
  hipLaunchKernelGGL(k_scan1, dim3(nb1), dim3(256), 0, stream, cnt, row_ptr, bsum, N);
  hipLaunchKernelGGL(k_scan2, dim3(1), dim3(256), 0, stream, bsum, nb1);
  hipLaunchKernelGGL(k_scan3, dim3((N + 256) / 256), dim3(256), 0, stream, row_ptr, bsum, N, E);
  hipLaunchKernelGGL(k_scatter, dim3((E + 255) / 256), dim3(256), 0, stream, src, dst, row_ptr,
                     fill, csr_src, E);
  hipLaunchKernelGGL(k_wmean, dim3((128 * 40 + 255) / 256), dim3(256), 0, stream, Wres2, wm);

  // layer 0
  hipLaunchKernelGGL((k_gemm<128>), dim3(nrb, 1), dim3(256), 0, stream, inputs, W0, F, N);
  hipLaunchKernelGGL((k_agg_fused<false>), dim3((N + 3) / 4), dim3(256), 0, stream, F, attn0,
                     row_ptr, csr_src, (const float*)nullptr, h1, N);
  // layer 1
  hipLaunchKernelGGL((k_gemm<128>), dim3(nrb, 1), dim3(256), 0, stream, h1, W1, F, N);
  hipLaunchKernelGGL((k_agg_fused<true>), dim3((N + 3) / 4), dim3(256), 0, stream, F, attn1,
                     row_ptr, csr_src, h1, h2, N);
  // layer 2
  hipLaunchKernelGGL((k_gemm<240>), dim3(nrb, 2), dim3(256), 0, stream, h2, W2, F, N);
  hipLaunchKernelGGL(k_resmean, dim3((N + 255) / 256), dim3(256), 0, stream, h2, wm, resm, N);
  hipLaunchKernelGGL(k_agg2_fused, dim3((N + 3) / 4), dim3(256), 0, stream, F, attn2, row_ptr,
                     csr_src, resm, (float*)d_out, N);
}

// Round 11
// 443.375 us; speedup vs baseline: 1.0121x; 1.0121x over previous
//
#include <hip/hip_runtime.h>
#include <math.h>

// GATv2, 3 layers. N=50000, E=500000, F_IN=128, H=4, D=32 (layers 0/1), HO=6, C=40 (layer 2).
// CSR-by-dst -> per-node fused softmax aggregation (no float atomics, no max tracking:
// logits are O(1) for this model), fp32 GEMMs, residual head-mean folded into small GEMM.
// Round 11: REVERT agg kernels to round-9 4-stream versions (round-10's 8-stream pushed
// VGPR 40->64, occupancy 57->39%, agg2 81->87 us: ILP exhausted at 4 streams).
// KEEP round-10 GEMM register-prefetch as the single variable vs the 437.4 us baseline.

#define LRELU(x) ((x) >= 0.f ? (x) : 0.2f * (x))

// ---------------- CSR build ----------------
__global__ void k_zero(int* __restrict__ cnt, int* __restrict__ fill, int N) {
  int i = blockIdx.x * blockDim.x + threadIdx.x;
  if (i < N) { cnt[i] = 0; fill[i] = 0; }
}

__global__ void k_count(const int* __restrict__ dst, int* __restrict__ cnt, int E) {
  int e = blockIdx.x * blockDim.x + threadIdx.x;
  if (e < E) atomicAdd(&cnt[dst[e]], 1);
}

__global__ void k_scan1(const int* __restrict__ cnt, int* __restrict__ row_ptr,
                        int* __restrict__ bsum, int N) {
  __shared__ int s[256];
  int tid = threadIdx.x;
  int i = blockIdx.x * 256 + tid;
  int v = (i < N) ? cnt[i] : 0;
  s[tid] = v;
  __syncthreads();
  for (int off = 1; off < 256; off <<= 1) {
    int t = (tid >= off) ? s[tid - off] : 0;
    __syncthreads();
    s[tid] += t;
    __syncthreads();
  }
  if (i < N) row_ptr[i] = s[tid] - v;
  if (tid == 255) bsum[blockIdx.x] = s[255];
}

__global__ void k_scan2(int* __restrict__ bsum, int nb) {
  __shared__ int s[256];
  int t = threadIdx.x;
  int v = (t < nb) ? bsum[t] : 0;
  s[t] = v;
  __syncthreads();
  for (int off = 1; off < 256; off <<= 1) {
    int tt = (t >= off) ? s[t - off] : 0;
    __syncthreads();
    s[t] += tt;
    __syncthreads();
  }
  if (t < nb) bsum[t] = s[t] - v;
}

__global__ void k_scan3(int* __restrict__ row_ptr, const int* __restrict__ bsum, int N, int E) {
  int i = blockIdx.x * blockDim.x + threadIdx.x;
  if (i < N) row_ptr[i] += bsum[i >> 8];
  else if (i == N) row_ptr[N] = E;
}

__global__ void k_scatter(const int* __restrict__ src, const int* __restrict__ dst,
                          const int* __restrict__ row_ptr, int* __restrict__ fill,
                          int* __restrict__ csr_src, int E) {
  int e = blockIdx.x * blockDim.x + threadIdx.x;
  if (e >= E) return;
  int d = dst[e];
  int pos = row_ptr[d] + atomicAdd(&fill[d], 1);
  csr_src[pos] = src[e];
}

// ---------------- Wres2 head-mean fold ----------------
__global__ void k_wmean(const float* __restrict__ wres2, float* __restrict__ wm) {
  int i = blockIdx.x * blockDim.x + threadIdx.x;
  if (i >= 128 * 40) return;
  int k = i / 40, c = i % 40;
  float s = 0.f;
#pragma unroll
  for (int ho = 0; ho < 6; ++ho) s += wres2[k * 240 + ho * 40 + c];
  wm[i] = s * (1.0f / 6.0f);
}

// ---------------- GEMM: C[N][LDC] = A[N][128] @ B[128][LDC], LDC in {128,240} ----------------
// 64x128 tile, 256 threads, 4x8/thread. Single LDS buffer BK=32, 2 barriers per chunk.
// Register prefetch: loads for chunk i+1 are issued BEFORE compute(i), drain during FMAs.
template <int LDC>
__global__ __launch_bounds__(256) void k_gemm(const float* __restrict__ A,
                                              const float* __restrict__ B,
                                              float* __restrict__ C, int N) {
  __shared__ __align__(16) float As[32][64];    // [k][row], 8KB
  __shared__ __align__(16) float Bs[32][128];   // [k][col], 16KB
  const int tid = threadIdx.x;
  const int row0 = blockIdx.x * 64;
  const int col_base = (blockIdx.y == 0) ? 0 : (LDC - 128);
  const int ty = tid >> 4, tx = tid & 15;
  const int r0 = ty * 4;
  const int arow = tid & 63;
  const int akc = (tid >> 6) * 8;   // 0,8,16,24 (wave-uniform)
  int gra = row0 + arow;
  if (gra >= N) gra = N - 1;
  const float* Ap = A + (size_t)gra * 128 + akc;
  const int f0 = tid * 4;
  const int br0 = f0 >> 7, bc0 = f0 & 127;

  float acc[4][8] = {};

  // prologue: chunk 0 into staging regs
  float4 a0 = *(const float4*)(Ap + 0);
  float4 a1 = *(const float4*)(Ap + 4);
  float4 bv0 = *(const float4*)&B[(size_t)(br0 + 0) * LDC + col_base + bc0];
  float4 bv1 = *(const float4*)&B[(size_t)(br0 + 8) * LDC + col_base + bc0];
  float4 bv2 = *(const float4*)&B[(size_t)(br0 + 16) * LDC + col_base + bc0];
  float4 bv3 = *(const float4*)&B[(size_t)(br0 + 24) * LDC + col_base + bc0];

#pragma unroll 1
  for (int i = 0; i < 4; ++i) {
    __syncthreads();   // previous chunk's LDS reads done
    As[akc + 0][arow] = a0.x;
    As[akc + 1][arow] = a0.y;
    As[akc + 2][arow] = a0.z;
    As[akc + 3][arow] = a0.w;
    As[akc + 4][arow] = a1.x;
    As[akc + 5][arow] = a1.y;
    As[akc + 6][arow] = a1.z;
    As[akc + 7][arow] = a1.w;
    *(float4*)&Bs[br0 + 0][bc0] = bv0;
    *(float4*)&Bs[br0 + 8][bc0] = bv1;
    *(float4*)&Bs[br0 + 16][bc0] = bv2;
    *(float4*)&Bs[br0 + 24][bc0] = bv3;
    if (i < 3) {
      const int kk = (i + 1) * 32;   // issue next-chunk loads; drain during compute
      a0 = *(const float4*)(Ap + kk);
      a1 = *(const float4*)(Ap + kk + 4);
      bv0 = *(const float4*)&B[(size_t)(kk + br0 + 0) * LDC + col_base + bc0];
      bv1 = *(const float4*)&B[(size_t)(kk + br0 + 8) * LDC + col_base + bc0];
      bv2 = *(const float4*)&B[(size_t)(kk + br0 + 16) * LDC + col_base + bc0];
      bv3 = *(const float4*)&B[(size_t)(kk + br0 + 24) * LDC + col_base + bc0];
    }
    __syncthreads();   // LDS chunk i visible
#pragma unroll
    for (int k = 0; k < 32; ++k) {
      float a[4], b[8];
      *(float4*)&a[0] = *(const float4*)&As[k][r0];
      *(float4*)&b[0] = *(const float4*)&Bs[k][tx * 4];
      *(float4*)&b[4] = *(const float4*)&Bs[k][64 + tx * 4];
#pragma unroll
      for (int ii = 0; ii < 4; ++ii)
#pragma unroll
        for (int jj = 0; jj < 8; ++jj) acc[ii][jj] += a[ii] * b[jj];
    }
  }

  const int gc_lo = col_base + tx * 4;
  const int gc_hi = col_base + 64 + tx * 4;
  const bool lo_ok = (blockIdx.y == 0) || (gc_lo >= 128);
#pragma unroll
  for (int i = 0; i < 4; ++i) {
    int gr = row0 + r0 + i;
    if (gr < N) {
      if (lo_ok) *(float4*)&C[(size_t)gr * LDC + gc_lo] = *(float4*)&acc[i][0];
      *(float4*)&C[(size_t)gr * LDC + gc_hi] = *(float4*)&acc[i][4];
    }
  }
}

// ---------------- res_mean[N][40] = A[N][128] @ Wm[128][40] ----------------
__global__ __launch_bounds__(256) void k_resmean(const float* __restrict__ A,
                                                 const float* __restrict__ Wm,
                                                 float* __restrict__ out, int N) {
  __shared__ float w[128 * 40];
  for (int i = threadIdx.x; i < 128 * 40; i += 256) w[i] = Wm[i];
  __syncthreads();
  int r = blockIdx.x * 256 + threadIdx.x;
  if (r >= N) return;
  float acc[40] = {};
  for (int k = 0; k < 128; k += 4) {
    float4 hv = *(const float4*)&A[(size_t)r * 128 + k];
#pragma unroll
    for (int j = 0; j < 40; ++j)
      acc[j] += hv.x * w[(k + 0) * 40 + j] + hv.y * w[(k + 1) * 40 + j] +
                hv.z * w[(k + 2) * 40 + j] + hv.w * w[(k + 3) * 40 + j];
  }
#pragma unroll
  for (int j = 0; j < 40; j += 4)
    *(float4*)&out[(size_t)r * 40 + j] = make_float4(acc[j], acc[j + 1], acc[j + 2], acc[j + 3]);
}

// ---------------- Fused edge softmax + aggregate, layers 0/1 (H=4, D=32) ----------------
// One wave per node; 4 edges per iteration (half-wave 0: {p,p+2}, half-wave 1: {p+1,p+3},
// two register streams each). NO max tracking: logits are O(1) -> plain exp accumulation.
template <bool RES>
__global__ __launch_bounds__(256) void k_agg_fused(const float* __restrict__ feat,
                                                   const float* __restrict__ attn,
                                                   const int* __restrict__ row_ptr,
                                                   const int* __restrict__ csr_src,
                                                   const float* __restrict__ hres,
                                                   float* __restrict__ out, int N) {
  int wid = (blockIdx.x * 256 + threadIdx.x) >> 6;
  bool nok = wid < N;
  int n = nok ? wid : (N - 1);
  int lane = threadIdx.x & 63;
  int half = lane >> 5;
  int c = (lane & 31) * 4;
  float4 fd = *(const float4*)&feat[(size_t)n * 128 + c];
  float4 av = *(const float4*)&attn[c];
  int p0 = row_ptr[n], p1 = row_ptr[n + 1];
  float4 zero = {0.f, 0.f, 0.f, 0.f};
  float sA = 0.f, sB = 0.f;
  float4 aA = zero, aB = zero;
  for (int p = p0; p < p1; p += 4) {
    int pA = p + half;
    int pB = p + 2 + half;
    bool vA = pA < p1, vB = pB < p1;
    int iA = csr_src[vA ? pA : p0];
    int iB = csr_src[vB ? pB : p0];
    float4 fA = *(const float4*)&feat[(size_t)iA * 128 + c];
    float4 fB = *(const float4*)&feat[(size_t)iB * 128 + c];
    float xA = av.x * LRELU(fA.x + fd.x) + av.y * LRELU(fA.y + fd.y) +
               av.z * LRELU(fA.z + fd.z) + av.w * LRELU(fA.w + fd.w);
    float xB = av.x * LRELU(fB.x + fd.x) + av.y * LRELU(fB.y + fd.y) +
               av.z * LRELU(fB.z + fd.z) + av.w * LRELU(fB.w + fd.w);
    xA += __shfl_xor(xA, 1);
    xB += __shfl_xor(xB, 1);
    xA += __shfl_xor(xA, 2);
    xB += __shfl_xor(xB, 2);
    xA += __shfl_xor(xA, 4);
    xB += __shfl_xor(xB, 4);
    float peA = vA ? __expf(xA) : 0.f;
    float peB = vB ? __expf(xB) : 0.f;
    sA += peA;
    aA.x += peA * fA.x;
    aA.y += peA * fA.y;
    aA.z += peA * fA.z;
    aA.w += peA * fA.w;
    sB += peB;
    aB.x += peB * fB.x;
    aB.y += peB * fB.y;
    aB.z += peB * fB.z;
    aB.w += peB * fB.w;
  }
  // merge in-half streams (plain add), then cross-half via shfl
  sA += sB;
  aA.x += aB.x; aA.y += aB.y; aA.z += aB.z; aA.w += aB.w;
  float s2 = __shfl_xor(sA, 32);
  float4 a2;
  a2.x = __shfl_xor(aA.x, 32);
  a2.y = __shfl_xor(aA.y, 32);
  a2.z = __shfl_xor(aA.z, 32);
  a2.w = __shfl_xor(aA.w, 32);
  float ssum = sA + s2;
  float inv = (p1 > p0) ? 1.0f / ssum : 0.f;
  float4 r;
  r.x = (aA.x + a2.x) * inv;
  r.y = (aA.y + a2.y) * inv;
  r.z = (aA.z + a2.z) * inv;
  r.w = (aA.w + a2.w) * inv;
  if (RES) {
    float4 hv = *(const float4*)&hres[(size_t)n * 128 + c];
    r.x += hv.x; r.y += hv.y; r.z += hv.z; r.w += hv.w;
  }
  r.x = r.x > 0.f ? r.x : expm1f(r.x);
  r.y = r.y > 0.f ? r.y : expm1f(r.y);
  r.z = r.z > 0.f ? r.z : expm1f(r.z);
  r.w = r.w > 0.f ? r.w : expm1f(r.w);
  if (half == 0 && nok) *(float4*)&out[(size_t)n * 128 + c] = r;
}

// ---------------- Fused layer 2 (HO=6, C=40) + head-mean + residual -> d_out ----------------
// ONE wave per node; lane = ho*10 + t (60 active), float4 at ho*40+t*4.
// FOUR independent accumulation streams (edges p..p+3), NO max tracking.
__global__ __launch_bounds__(256) void k_agg2_fused(const float* __restrict__ feat2,
                                                    const float* __restrict__ attn2,
                                                    const int* __restrict__ row_ptr,
                                                    const int* __restrict__ csr_src,
                                                    const float* __restrict__ resm,
                                                    float* __restrict__ out, int N) {
  __shared__ float rs[4][240];
  int w = threadIdx.x >> 6;
  int wid = blockIdx.x * 4 + w;
  bool nok = wid < N;
  int n = nok ? wid : (N - 1);
  int lane = threadIdx.x & 63;
  bool act = lane < 60;
  int ho = lane / 10, t = lane % 10;
  int g0 = ho * 10;
  int fo = act ? (ho * 40 + t * 4) : 0;
  float4 zero = {0.f, 0.f, 0.f, 0.f};
  float4 fd = act ? *(const float4*)&feat2[(size_t)n * 240 + fo] : zero;
  float4 av = act ? *(const float4*)&attn2[fo] : zero;
  int p0 = row_ptr[n], p1 = row_ptr[n + 1];
  float s_[4];
  float4 a_[4];
#pragma unroll
  for (int j = 0; j < 4; ++j) { s_[j] = 0.f; a_[j] = zero; }
  for (int p = p0; p < p1; p += 4) {
    int idx[4];
    bool val[4];
#pragma unroll
    for (int j = 0; j < 4; ++j) {
      int pp = p + j;
      val[j] = pp < p1;
      idx[j] = csr_src[val[j] ? pp : p];
    }
    float4 f_[4];
#pragma unroll
    for (int j = 0; j < 4; ++j) f_[j] = *(const float4*)&feat2[(size_t)idx[j] * 240 + fo];
    float x_[4], aa_[4], S_[4];
#pragma unroll
    for (int j = 0; j < 4; ++j)
      x_[j] = av.x * LRELU(f_[j].x + fd.x) + av.y * LRELU(f_[j].y + fd.y) +
              av.z * LRELU(f_[j].z + fd.z) + av.w * LRELU(f_[j].w + fd.w);
    // 10-lane segmented reduce, 4 streams interleaved
#pragma unroll
    for (int j = 0; j < 4; ++j) aa_[j] = x_[j] + __shfl(x_[j], lane + 5);
#pragma unroll
    for (int j = 0; j < 4; ++j) S_[j] = aa_[j] + __shfl(aa_[j], lane + 1);
#pragma unroll
    for (int j = 0; j < 4; ++j) S_[j] = S_[j] + __shfl(S_[j], lane + 2);
#pragma unroll
    for (int j = 0; j < 4; ++j) S_[j] = S_[j] + __shfl(aa_[j], lane + 4);
#pragma unroll
    for (int j = 0; j < 4; ++j) {
      float l = __shfl(S_[j], g0);
      float pe = val[j] ? __expf(l) : 0.f;
      s_[j] += pe;
      a_[j].x += pe * f_[j].x;
      a_[j].y += pe * f_[j].y;
      a_[j].z += pe * f_[j].z;
      a_[j].w += pe * f_[j].w;
    }
  }
  float ssum = (s_[0] + s_[1]) + (s_[2] + s_[3]);
  float4 at;
  at.x = (a_[0].x + a_[1].x) + (a_[2].x + a_[3].x);
  at.y = (a_[0].y + a_[1].y) + (a_[2].y + a_[3].y);
  at.z = (a_[0].z + a_[1].z) + (a_[2].z + a_[3].z);
  at.w = (a_[0].w + a_[1].w) + (a_[2].w + a_[3].w);
  float inv = (p1 > p0) ? 1.0f / ssum : 0.f;
  float4 r;
  r.x = at.x * inv;
  r.y = at.y * inv;
  r.z = at.z * inv;
  r.w = at.w * inv;
  if (act) *(float4*)&rs[w][fo] = r;
  __syncthreads();
  if (lane < 10 && nok) {
#pragma unroll
    for (int k = 0; k < 4; ++k) {
      int cc = t * 4 + k;
      float v = (rs[w][cc] + rs[w][40 + cc] + rs[w][80 + cc] + rs[w][120 + cc] +
                 rs[w][160 + cc] + rs[w][200 + cc]) * (1.0f / 6.0f) +
                resm[(size_t)n * 40 + cc];
      out[(size_t)n * 40 + cc] = v;
    }
  }
}

// ---------------- host ----------------
extern "C" void kernel_launch(void* const* d_in, const int* in_sizes, int n_in,
                              void* d_out, int out_size, void* d_ws, size_t ws_size,
                              hipStream_t stream) {
  const float* inputs = (const float*)d_in[0];
  const int* src = (const int*)d_in[1];
  const int* dst = (const int*)d_in[2];
  const float* W0 = (const float*)d_in[3];
  const float* attn0 = (const float*)d_in[4];
  const float* W1 = (const float*)d_in[5];
  const float* attn1 = (const float*)d_in[6];
  const float* W2 = (const float*)d_in[7];
  const float* attn2 = (const float*)d_in[8];
  const float* Wres2 = (const float*)d_in[9];
  const int N = in_sizes[0] / 128;
  const int E = in_sizes[1];

  char* base = (char*)d_ws;
  size_t off = 0;
  auto alloc = [&](size_t bytes) -> void* {
    void* q = base + off;
    off += (bytes + 255) & ~(size_t)255;
    return q;
  };
  int* cnt = (int*)alloc((size_t)N * 4);
  int* fill = (int*)alloc((size_t)N * 4);
  int* row_ptr = (int*)alloc((size_t)(N + 1) * 4);
  int* bsum = (int*)alloc(1024 * 4);
  int* csr_src = (int*)alloc((size_t)E * 4);
  float* F = (float*)alloc((size_t)N * 240 * 4);
  float* h1 = (float*)alloc((size_t)N * 128 * 4);
  float* h2 = (float*)alloc((size_t)N * 128 * 4);
  float* resm = (float*)alloc((size_t)N * 40 * 4);
  float* wm = (float*)alloc(128 * 40 * 4);
  (void)ws_size;

  const int nb1 = (N + 255) / 256;
  const int nrb = (N + 63) / 64;

  hipLaunchKernelGGL(k_zero, dim3((N + 255) / 256), dim3(256), 0, stream, cnt, fill, N);
  hipLaunchKernelGGL(k_count, dim3((E + 255) / 256), dim3(256), 0, stream, dst, cnt, E);
  hipLaunchKernelGGL(k_scan1, dim3(nb1), dim3(256), 0, stream, cnt, row_ptr, bsum, N);
  hipLaunchKernelGGL(k_scan2, dim3(1), dim3(256), 0, stream, bsum, nb1);
  hipLaunchKernelGGL(k_scan3, dim3((N + 256) / 256), dim3(256), 0, stream, row_ptr, bsum, N, E);
  hipLaunchKernelGGL(k_scatter, dim3((E + 255) / 256), dim3(256), 0, stream, src, dst, row_ptr,
                     fill, csr_src, E);
  hipLaunchKernelGGL(k_wmean, dim3((128 * 40 + 255) / 256), dim3(256), 0, stream, Wres2, wm);

  // layer 0
  hipLaunchKernelGGL((k_gemm<128>), dim3(nrb, 1), dim3(256), 0, stream, inputs, W0, F, N);
  hipLaunchKernelGGL((k_agg_fused<false>), dim3((N + 3) / 4), dim3(256), 0, stream, F, attn0,
                     row_ptr, csr_src, (const float*)nullptr, h1, N);
  // layer 1
  hipLaunchKernelGGL((k_gemm<128>), dim3(nrb, 1), dim3(256), 0, stream, h1, W1, F, N);
  hipLaunchKernelGGL((k_agg_fused<true>), dim3((N + 3) / 4), dim3(256), 0, stream, F, attn1,
                     row_ptr, csr_src, h1, h2, N);
  // layer 2
  hipLaunchKernelGGL((k_gemm<240>), dim3(nrb, 2), dim3(256), 0, stream, h2, W2, F, N);
  hipLaunchKernelGGL(k_resmean, dim3((N + 255) / 256), dim3(256), 0, stream, h2, wm, resm, N);
  hipLaunchKernelGGL(k_agg2_fused, dim3((N + 3) / 4), dim3(256), 0, stream, F, attn2, row_ptr,
                     csr_src, resm, (float*)d_out, N);
}

// Round 12
// 436.537 us; speedup vs baseline: 1.0279x; 1.0157x over previous
//
#include <hip/hip_runtime.h>
#include <math.h>

// GATv2, 3 layers. N=50000, E=500000, F_IN=128, H=4, D=32 (layers 0/1), HO=6, C=40 (layer 2).
// CSR-by-dst -> per-node fused softmax aggregation (no float atomics, no max tracking:
// logits are O(1) for this model), fp32 GEMMs, residual head-mean folded into small GEMM.
// Round 12: (a) REVERT GEMM register-prefetch (round-11 isolated it: +6 us, live-range
// cost > latency gain) back to validated round-8 BK=32 between-barriers form.
// (b) agg2: barrier-free epilogue -- cross-head mean via 3-step lane fold (+30,+10,+20)
// instead of LDS+__syncthreads; 4 waves per block fully decoupled, LDS=0.

#define LRELU(x) ((x) >= 0.f ? (x) : 0.2f * (x))

// ---------------- CSR build ----------------
__global__ void k_zero(int* __restrict__ cnt, int* __restrict__ fill, int N) {
  int i = blockIdx.x * blockDim.x + threadIdx.x;
  if (i < N) { cnt[i] = 0; fill[i] = 0; }
}

__global__ void k_count(const int* __restrict__ dst, int* __restrict__ cnt, int E) {
  int e = blockIdx.x * blockDim.x + threadIdx.x;
  if (e < E) atomicAdd(&cnt[dst[e]], 1);
}

__global__ void k_scan1(const int* __restrict__ cnt, int* __restrict__ row_ptr,
                        int* __restrict__ bsum, int N) {
  __shared__ int s[256];
  int tid = threadIdx.x;
  int i = blockIdx.x * 256 + tid;
  int v = (i < N) ? cnt[i] : 0;
  s[tid] = v;
  __syncthreads();
  for (int off = 1; off < 256; off <<= 1) {
    int t = (tid >= off) ? s[tid - off] : 0;
    __syncthreads();
    s[tid] += t;
    __syncthreads();
  }
  if (i < N) row_ptr[i] = s[tid] - v;
  if (tid == 255) bsum[blockIdx.x] = s[255];
}

__global__ void k_scan2(int* __restrict__ bsum, int nb) {
  __shared__ int s[256];
  int t = threadIdx.x;
  int v = (t < nb) ? bsum[t] : 0;
  s[t] = v;
  __syncthreads();
  for (int off = 1; off < 256; off <<= 1) {
    int tt = (t >= off) ? s[t - off] : 0;
    __syncthreads();
    s[t] += tt;
    __syncthreads();
  }
  if (t < nb) bsum[t] = s[t] - v;
}

__global__ void k_scan3(int* __restrict__ row_ptr, const int* __restrict__ bsum, int N, int E) {
  int i = blockIdx.x * blockDim.x + threadIdx.x;
  if (i < N) row_ptr[i] += bsum[i >> 8];
  else if (i == N) row_ptr[N] = E;
}

__global__ void k_scatter(const int* __restrict__ src, const int* __restrict__ dst,
                          const int* __restrict__ row_ptr, int* __restrict__ fill,
                          int* __restrict__ csr_src, int E) {
  int e = blockIdx.x * blockDim.x + threadIdx.x;
  if (e >= E) return;
  int d = dst[e];
  int pos = row_ptr[d] + atomicAdd(&fill[d], 1);
  csr_src[pos] = src[e];
}

// ---------------- Wres2 head-mean fold ----------------
__global__ void k_wmean(const float* __restrict__ wres2, float* __restrict__ wm) {
  int i = blockIdx.x * blockDim.x + threadIdx.x;
  if (i >= 128 * 40) return;
  int k = i / 40, c = i % 40;
  float s = 0.f;
#pragma unroll
  for (int ho = 0; ho < 6; ++ho) s += wres2[k * 240 + ho * 40 + c];
  wm[i] = s * (1.0f / 6.0f);
}

// ---------------- GEMM: C[N][LDC] = A[N][128] @ B[128][LDC], LDC in {128,240} ----------------
// 64x128 tile (col tile via blockIdx.y: base 0 or LDC-128), 256 threads, 4x8/thread.
// Single LDS buffer, BK=32: 2 barriers per chunk, 4 chunks, 1024 FMA between barriers.
// (round-8 validated form; register-prefetch variant measured +6 us in round 11)
template <int LDC>
__global__ __launch_bounds__(256) void k_gemm(const float* __restrict__ A,
                                              const float* __restrict__ B,
                                              float* __restrict__ C, int N) {
  __shared__ __align__(16) float As[32][64];    // [k][row], 8KB
  __shared__ __align__(16) float Bs[32][128];   // [k][col], 16KB
  const int tid = threadIdx.x;
  const int row0 = blockIdx.x * 64;
  const int col_base = (blockIdx.y == 0) ? 0 : (LDC - 128);
  const int ty = tid >> 4, tx = tid & 15;
  const int r0 = ty * 4;
  const int arow = tid & 63;
  const int akc = (tid >> 6) * 8;   // 0,8,16,24 (wave-uniform)
  int gra = row0 + arow;
  if (gra >= N) gra = N - 1;
  const float* Ap = A + (size_t)gra * 128 + akc;
  const int f0 = tid * 4;
  const int br0 = f0 >> 7, bc0 = f0 & 127;

  float acc[4][8] = {};

#pragma unroll 1
  for (int kk = 0; kk < 128; kk += 32) {
    __syncthreads();
    float4 a0 = *(const float4*)(Ap + kk);
    float4 a1 = *(const float4*)(Ap + kk + 4);
    float4 bv0 = *(const float4*)&B[(size_t)(kk + br0 + 0) * LDC + col_base + bc0];
    float4 bv1 = *(const float4*)&B[(size_t)(kk + br0 + 8) * LDC + col_base + bc0];
    float4 bv2 = *(const float4*)&B[(size_t)(kk + br0 + 16) * LDC + col_base + bc0];
    float4 bv3 = *(const float4*)&B[(size_t)(kk + br0 + 24) * LDC + col_base + bc0];
    As[akc + 0][arow] = a0.x;
    As[akc + 1][arow] = a0.y;
    As[akc + 2][arow] = a0.z;
    As[akc + 3][arow] = a0.w;
    As[akc + 4][arow] = a1.x;
    As[akc + 5][arow] = a1.y;
    As[akc + 6][arow] = a1.z;
    As[akc + 7][arow] = a1.w;
    *(float4*)&Bs[br0 + 0][bc0] = bv0;
    *(float4*)&Bs[br0 + 8][bc0] = bv1;
    *(float4*)&Bs[br0 + 16][bc0] = bv2;
    *(float4*)&Bs[br0 + 24][bc0] = bv3;
    __syncthreads();
#pragma unroll
    for (int k = 0; k < 32; ++k) {
      float a[4], b[8];
      *(float4*)&a[0] = *(const float4*)&As[k][r0];
      *(float4*)&b[0] = *(const float4*)&Bs[k][tx * 4];
      *(float4*)&b[4] = *(const float4*)&Bs[k][64 + tx * 4];
#pragma unroll
      for (int ii = 0; ii < 4; ++ii)
#pragma unroll
        for (int jj = 0; jj < 8; ++jj) acc[ii][jj] += a[ii] * b[jj];
    }
  }

  const int gc_lo = col_base + tx * 4;
  const int gc_hi = col_base + 64 + tx * 4;
  const bool lo_ok = (blockIdx.y == 0) || (gc_lo >= 128);
#pragma unroll
  for (int i = 0; i < 4; ++i) {
    int gr = row0 + r0 + i;
    if (gr < N) {
      if (lo_ok) *(float4*)&C[(size_t)gr * LDC + gc_lo] = *(float4*)&acc[i][0];
      *(float4*)&C[(size_t)gr * LDC + gc_hi] = *(float4*)&acc[i][4];
    }
  }
}

// ---------------- res_mean[N][40] = A[N][128] @ Wm[128][40] ----------------
__global__ __launch_bounds__(256) void k_resmean(const float* __restrict__ A,
                                                 const float* __restrict__ Wm,
                                                 float* __restrict__ out, int N) {
  __shared__ float w[128 * 40];
  for (int i = threadIdx.x; i < 128 * 40; i += 256) w[i] = Wm[i];
  __syncthreads();
  int r = blockIdx.x * 256 + threadIdx.x;
  if (r >= N) return;
  float acc[40] = {};
  for (int k = 0; k < 128; k += 4) {
    float4 hv = *(const float4*)&A[(size_t)r * 128 + k];
#pragma unroll
    for (int j = 0; j < 40; ++j)
      acc[j] += hv.x * w[(k + 0) * 40 + j] + hv.y * w[(k + 1) * 40 + j] +
                hv.z * w[(k + 2) * 40 + j] + hv.w * w[(k + 3) * 40 + j];
  }
#pragma unroll
  for (int j = 0; j < 40; j += 4)
    *(float4*)&out[(size_t)r * 40 + j] = make_float4(acc[j], acc[j + 1], acc[j + 2], acc[j + 3]);
}

// ---------------- Fused edge softmax + aggregate, layers 0/1 (H=4, D=32) ----------------
// One wave per node; 4 edges per iteration (half-wave 0: {p,p+2}, half-wave 1: {p+1,p+3},
// two register streams each). NO max tracking: logits are O(1) -> plain exp accumulation.
template <bool RES>
__global__ __launch_bounds__(256) void k_agg_fused(const float* __restrict__ feat,
                                                   const float* __restrict__ attn,
                                                   const int* __restrict__ row_ptr,
                                                   const int* __restrict__ csr_src,
                                                   const float* __restrict__ hres,
                                                   float* __restrict__ out, int N) {
  int wid = (blockIdx.x * 256 + threadIdx.x) >> 6;
  bool nok = wid < N;
  int n = nok ? wid : (N - 1);
  int lane = threadIdx.x & 63;
  int half = lane >> 5;
  int c = (lane & 31) * 4;
  float4 fd = *(const float4*)&feat[(size_t)n * 128 + c];
  float4 av = *(const float4*)&attn[c];
  int p0 = row_ptr[n], p1 = row_ptr[n + 1];
  float4 zero = {0.f, 0.f, 0.f, 0.f};
  float sA = 0.f, sB = 0.f;
  float4 aA = zero, aB = zero;
  for (int p = p0; p < p1; p += 4) {
    int pA = p + half;
    int pB = p + 2 + half;
    bool vA = pA < p1, vB = pB < p1;
    int iA = csr_src[vA ? pA : p0];
    int iB = csr_src[vB ? pB : p0];
    float4 fA = *(const float4*)&feat[(size_t)iA * 128 + c];
    float4 fB = *(const float4*)&feat[(size_t)iB * 128 + c];
    float xA = av.x * LRELU(fA.x + fd.x) + av.y * LRELU(fA.y + fd.y) +
               av.z * LRELU(fA.z + fd.z) + av.w * LRELU(fA.w + fd.w);
    float xB = av.x * LRELU(fB.x + fd.x) + av.y * LRELU(fB.y + fd.y) +
               av.z * LRELU(fB.z + fd.z) + av.w * LRELU(fB.w + fd.w);
    xA += __shfl_xor(xA, 1);
    xB += __shfl_xor(xB, 1);
    xA += __shfl_xor(xA, 2);
    xB += __shfl_xor(xB, 2);
    xA += __shfl_xor(xA, 4);
    xB += __shfl_xor(xB, 4);
    float peA = vA ? __expf(xA) : 0.f;
    float peB = vB ? __expf(xB) : 0.f;
    sA += peA;
    aA.x += peA * fA.x;
    aA.y += peA * fA.y;
    aA.z += peA * fA.z;
    aA.w += peA * fA.w;
    sB += peB;
    aB.x += peB * fB.x;
    aB.y += peB * fB.y;
    aB.z += peB * fB.z;
    aB.w += peB * fB.w;
  }
  // merge in-half streams (plain add), then cross-half via shfl
  sA += sB;
  aA.x += aB.x; aA.y += aB.y; aA.z += aB.z; aA.w += aB.w;
  float s2 = __shfl_xor(sA, 32);
  float4 a2;
  a2.x = __shfl_xor(aA.x, 32);
  a2.y = __shfl_xor(aA.y, 32);
  a2.z = __shfl_xor(aA.z, 32);
  a2.w = __shfl_xor(aA.w, 32);
  float ssum = sA + s2;
  float inv = (p1 > p0) ? 1.0f / ssum : 0.f;
  float4 r;
  r.x = (aA.x + a2.x) * inv;
  r.y = (aA.y + a2.y) * inv;
  r.z = (aA.z + a2.z) * inv;
  r.w = (aA.w + a2.w) * inv;
  if (RES) {
    float4 hv = *(const float4*)&hres[(size_t)n * 128 + c];
    r.x += hv.x; r.y += hv.y; r.z += hv.z; r.w += hv.w;
  }
  r.x = r.x > 0.f ? r.x : expm1f(r.x);
  r.y = r.y > 0.f ? r.y : expm1f(r.y);
  r.z = r.z > 0.f ? r.z : expm1f(r.z);
  r.w = r.w > 0.f ? r.w : expm1f(r.w);
  if (half == 0 && nok) *(float4*)&out[(size_t)n * 128 + c] = r;
}

// ---------------- Fused layer 2 (HO=6, C=40) + head-mean + residual -> d_out ----------------
// ONE wave per node; lane = ho*10 + t (60 active), float4 at ho*40+t*4.
// FOUR independent accumulation streams (edges p..p+3), NO max tracking.
// Barrier-free epilogue: cross-head mean via 3-step lane fold (+30, +10, +20); no LDS.
__global__ __launch_bounds__(256) void k_agg2_fused(const float* __restrict__ feat2,
                                                    const float* __restrict__ attn2,
                                                    const int* __restrict__ row_ptr,
                                                    const int* __restrict__ csr_src,
                                                    const float* __restrict__ resm,
                                                    float* __restrict__ out, int N) {
  int wid = blockIdx.x * 4 + (threadIdx.x >> 6);
  bool nok = wid < N;
  int n = nok ? wid : (N - 1);
  int lane = threadIdx.x & 63;
  bool act = lane < 60;
  int ho = lane / 10, t = lane % 10;
  int g0 = ho * 10;
  int fo = act ? (ho * 40 + t * 4) : 0;
  float4 zero = {0.f, 0.f, 0.f, 0.f};
  float4 fd = act ? *(const float4*)&feat2[(size_t)n * 240 + fo] : zero;
  float4 av = act ? *(const float4*)&attn2[fo] : zero;
  int p0 = row_ptr[n], p1 = row_ptr[n + 1];
  float s_[4];
  float4 a_[4];
#pragma unroll
  for (int j = 0; j < 4; ++j) { s_[j] = 0.f; a_[j] = zero; }
  for (int p = p0; p < p1; p += 4) {
    int idx[4];
    bool val[4];
#pragma unroll
    for (int j = 0; j < 4; ++j) {
      int pp = p + j;
      val[j] = pp < p1;
      idx[j] = csr_src[val[j] ? pp : p];
    }
    float4 f_[4];
#pragma unroll
    for (int j = 0; j < 4; ++j) f_[j] = *(const float4*)&feat2[(size_t)idx[j] * 240 + fo];
    float x_[4], aa_[4], S_[4];
#pragma unroll
    for (int j = 0; j < 4; ++j)
      x_[j] = av.x * LRELU(f_[j].x + fd.x) + av.y * LRELU(f_[j].y + fd.y) +
              av.z * LRELU(f_[j].z + fd.z) + av.w * LRELU(f_[j].w + fd.w);
    // 10-lane segmented reduce, 4 streams interleaved
#pragma unroll
    for (int j = 0; j < 4; ++j) aa_[j] = x_[j] + __shfl(x_[j], lane + 5);
#pragma unroll
    for (int j = 0; j < 4; ++j) S_[j] = aa_[j] + __shfl(aa_[j], lane + 1);
#pragma unroll
    for (int j = 0; j < 4; ++j) S_[j] = S_[j] + __shfl(S_[j], lane + 2);
#pragma unroll
    for (int j = 0; j < 4; ++j) S_[j] = S_[j] + __shfl(aa_[j], lane + 4);
#pragma unroll
    for (int j = 0; j < 4; ++j) {
      float l = __shfl(S_[j], g0);
      float pe = val[j] ? __expf(l) : 0.f;
      s_[j] += pe;
      a_[j].x += pe * f_[j].x;
      a_[j].y += pe * f_[j].y;
      a_[j].z += pe * f_[j].z;
      a_[j].w += pe * f_[j].w;
    }
  }
  float ssum = (s_[0] + s_[1]) + (s_[2] + s_[3]);
  float4 at;
  at.x = (a_[0].x + a_[1].x) + (a_[2].x + a_[3].x);
  at.y = (a_[0].y + a_[1].y) + (a_[2].y + a_[3].y);
  at.z = (a_[0].z + a_[1].z) + (a_[2].z + a_[3].z);
  at.w = (a_[0].w + a_[1].w) + (a_[2].w + a_[3].w);
  float inv = (p1 > p0) ? 1.0f / ssum : 0.f;
  float4 r;
  r.x = at.x * inv;
  r.y = at.y * inv;
  r.z = at.z * inv;
  r.w = at.w * inv;
  // cross-head mean: lanes ho*10+t fold onto lanes 0-9 (t = lane)
  // step1: r += r(lane+30)  -> lanes 0-29 hold ho + (ho+3)
  float4 y;
  y.x = __shfl(r.x, lane + 30);
  y.y = __shfl(r.y, lane + 30);
  y.z = __shfl(r.z, lane + 30);
  y.w = __shfl(r.w, lane + 30);
  r.x += y.x; r.y += y.y; r.z += y.z; r.w += y.w;
  // step2/3: lanes 0-9 add lanes +10 and +20
  float4 z1, z2;
  z1.x = __shfl(r.x, lane + 10);
  z1.y = __shfl(r.y, lane + 10);
  z1.z = __shfl(r.z, lane + 10);
  z1.w = __shfl(r.w, lane + 10);
  z2.x = __shfl(r.x, lane + 20);
  z2.y = __shfl(r.y, lane + 20);
  z2.z = __shfl(r.z, lane + 20);
  z2.w = __shfl(r.w, lane + 20);
  if (lane < 10 && nok) {
    float4 o;
    const float4 rm = *(const float4*)&resm[(size_t)n * 40 + lane * 4];
    o.x = (r.x + z1.x + z2.x) * (1.0f / 6.0f) + rm.x;
    o.y = (r.y + z1.y + z2.y) * (1.0f / 6.0f) + rm.y;
    o.z = (r.z + z1.z + z2.z) * (1.0f / 6.0f) + rm.z;
    o.w = (r.w + z1.w + z2.w) * (1.0f / 6.0f) + rm.w;
    *(float4*)&out[(size_t)n * 40 + lane * 4] = o;
  }
}

// ---------------- host ----------------
extern "C" void kernel_launch(void* const* d_in, const int* in_sizes, int n_in,
                              void* d_out, int out_size, void* d_ws, size_t ws_size,
                              hipStream_t stream) {
  const float* inputs = (const float*)d_in[0];
  const int* src = (const int*)d_in[1];
  const int* dst = (const int*)d_in[2];
  const float* W0 = (const float*)d_in[3];
  const float* attn0 = (const float*)d_in[4];
  const float* W1 = (const float*)d_in[5];
  const float* attn1 = (const float*)d_in[6];
  const float* W2 = (const float*)d_in[7];
  const float* attn2 = (const float*)d_in[8];
  const float* Wres2 = (const float*)d_in[9];
  const int N = in_sizes[0] / 128;
  const int E = in_sizes[1];

  char* base = (char*)d_ws;
  size_t off = 0;
  auto alloc = [&](size_t bytes) -> void* {
    void* q = base + off;
    off += (bytes + 255) & ~(size_t)255;
    return q;
  };
  int* cnt = (int*)alloc((size_t)N * 4);
  int* fill = (int*)alloc((size_t)N * 4);
  int* row_ptr = (int*)alloc((size_t)(N + 1) * 4);
  int* bsum = (int*)alloc(1024 * 4);
  int* csr_src = (int*)alloc((size_t)E * 4);
  float* F = (float*)alloc((size_t)N * 240 * 4);
  float* h1 = (float*)alloc((size_t)N * 128 * 4);
  float* h2 = (float*)alloc((size_t)N * 128 * 4);
  float* resm = (float*)alloc((size_t)N * 40 * 4);
  float* wm = (float*)alloc(128 * 40 * 4);
  (void)ws_size;

  const int nb1 = (N + 255) / 256;
  const int nrb = (N + 63) / 64;

  hipLaunchKernelGGL(k_zero, dim3((N + 255) / 256), dim3(256), 0, stream, cnt, fill, N);
  hipLaunchKernelGGL(k_count, dim3((E + 255) / 256), dim3(256), 0, stream, dst, cnt, E);
  hipLaunchKernelGGL(k_scan1, dim3(nb1), dim3(256), 0, stream, cnt, row_ptr, bsum, N);
  hipLaunchKernelGGL(k_scan2, dim3(1), dim3(256), 0, stream, bsum, nb1);
  hipLaunchKernelGGL(k_scan3, dim3((N + 256) / 256), dim3(256), 0, stream, row_ptr, bsum, N, E);
  hipLaunchKernelGGL(k_scatter, dim3((E + 255) / 256), dim3(256), 0, stream, src, dst, row_ptr,
                     fill, csr_src, E);
  hipLaunchKernelGGL(k_wmean, dim3((128 * 40 + 255) / 256), dim3(256), 0, stream, Wres2, wm);

  // layer 0
  hipLaunchKernelGGL((k_gemm<128>), dim3(nrb, 1), dim3(256), 0, stream, inputs, W0, F, N);
  hipLaunchKernelGGL((k_agg_fused<false>), dim3((N + 3) / 4), dim3(256), 0, stream, F, attn0,
                     row_ptr, csr_src, (const float*)nullptr, h1, N);
  // layer 1
  hipLaunchKernelGGL((k_gemm<128>), dim3(nrb, 1), dim3(256), 0, stream, h1, W1, F, N);
  hipLaunchKernelGGL((k_agg_fused<true>), dim3((N + 3) / 4), dim3(256), 0, stream, F, attn1,
                     row_ptr, csr_src, h1, h2, N);
  // layer 2
  hipLaunchKernelGGL((k_gemm<240>), dim3(nrb, 2), dim3(256), 0, stream, h2, W2, F, N);
  hipLaunchKernelGGL(k_resmean, dim3((N + 255) / 256), dim3(256), 0, stream, h2, wm, resm, N);
  hipLaunchKernelGGL(k_agg2_fused, dim3((N + 3) / 4), dim3(256), 0, stream, F, attn2, row_ptr,
                     csr_src, resm, (float*)d_out, N);
}